// Round 1
// 211.709 us; speedup vs baseline: 1.0261x; 1.0261x over previous
//
#include <hip/hip_runtime.h>

typedef _Float16 half8 __attribute__((ext_vector_type(8)));
typedef _Float16 half4 __attribute__((ext_vector_type(4)));
typedef _Float16 half2v __attribute__((ext_vector_type(2)));
typedef float floatx4 __attribute__((ext_vector_type(4)));
typedef unsigned int uint2v __attribute__((ext_vector_type(2)));
typedef unsigned int uint4v __attribute__((ext_vector_type(4)));

__device__ __forceinline__ void gl_lds16(const _Float16* g, _Float16* l) {
    __builtin_amdgcn_global_load_lds(
        (const __attribute__((address_space(1))) void*)g,
        (__attribute__((address_space(3))) void*)l, 16, 0, 0);
}

__device__ __forceinline__ half2v cvt_pk(float a, float b) {
    return __builtin_bit_cast(half2v, __builtin_amdgcn_cvt_pkrtz(a, b));
}

__device__ __forceinline__ half2v rcp2(half2v d) {
#if __has_builtin(__builtin_amdgcn_rcph)
    half2v r;
    r[0] = __builtin_amdgcn_rcph(d[0]);
    r[1] = __builtin_amdgcn_rcph(d[1]);
    return r;
#else
    half2v r;
    r[0] = (_Float16)__builtin_amdgcn_rcpf((float)d[0]);
    r[1] = (_Float16)__builtin_amdgcn_rcpf((float)d[1]);
    return r;
#endif
}

__device__ __forceinline__ float dot2acc(half2v a, float acc) {
#if __has_builtin(__builtin_amdgcn_fdot2)
    const half2v one = {(_Float16)1.0f, (_Float16)1.0f};
    return __builtin_amdgcn_fdot2(a, one, acc, false);
#else
    return acc + (float)a[0] + (float)a[1];
#endif
}

// concat 4 packed half2 (each one dword) into a half8 — no element inserts
__device__ __forceinline__ half8 from4(half2v a, half2v b, half2v c, half2v d) {
    uint4v u = {__builtin_bit_cast(unsigned int, a), __builtin_bit_cast(unsigned int, b),
                __builtin_bit_cast(unsigned int, c), __builtin_bit_cast(unsigned int, d)};
    return __builtin_bit_cast(half8, u);
}

// concat two half4 (two dword-pairs) into a half8 — no element inserts
__device__ __forceinline__ half8 from_lohi(half4 lo, half4 hi) {
    uint2v l = __builtin_bit_cast(uint2v, lo);
    uint2v h = __builtin_bit_cast(uint2v, hi);
    uint4v u = {l[0], l[1], h[0], h[1]};
    return __builtin_bit_cast(half8, u);
}

// ---------------- fp32 -> fp16 convert: x and w_qkv fused (runs BEFORE gemm_qkv) -
__global__ __launch_bounds__(256) void cvt_xw(const floatx4* __restrict__ x,
                                              const floatx4* __restrict__ wq,
                                              half4* __restrict__ xh,
                                              half4* __restrict__ wqh) {
    int i = blockIdx.x * 256 + threadIdx.x;   // 0..1835007
    floatx4 v;
    half4 h;
    if (i < 1048576) {
        v = x[i];
#pragma unroll
        for (int j = 0; j < 4; ++j) h[j] = (_Float16)v[j];
        xh[i] = h;
    } else {
        int j4 = i - 1048576;
        v = wq[j4];
#pragma unroll
        for (int j = 0; j < 4; ++j) h[j] = (_Float16)v[j];
        wqh[j4] = h;
    }
}

// wout cvt — MUST run after gemm_qkv (woh aliases wqh)
__global__ __launch_bounds__(256) void cvt_f32_f16(const floatx4* __restrict__ in,
                                                   half4* __restrict__ out, int n4) {
    int i = blockIdx.x * 256 + threadIdx.x;
    if (i >= n4) return;
    floatx4 v = in[i];
    half4 h;
#pragma unroll
    for (int j = 0; j < 4; ++j) h[j] = (_Float16)v[j];
    out[i] = h;
}

// ---------------- GEMM1: qkv = xh @ wqh^T -> head-major q/k/vt (fp16 in/out) -----
// M=4096, N=3072, K=1024. 128x128 tile, BK=32, 256 thr, DMA staging.
__global__ __launch_bounds__(256) void gemm_qkv(const _Float16* __restrict__ A,
                                                const _Float16* __restrict__ B,
                                                _Float16* __restrict__ qh,
                                                _Float16* __restrict__ kh,
                                                _Float16* __restrict__ vth) {
    const int K = 1024;
    __shared__ _Float16 SH[128 * 68];   // As 8KB | Bs 8KB; epilogue 128x68
    _Float16* As = SH;
    _Float16* Bs = SH + 4096;
    const int t = threadIdx.x;
    const int lane = t & 63, w = t >> 6;
    const int l15 = lane & 15, quad = lane >> 4;
    const int wm = w >> 1, wn = w & 1;
    const int m0 = blockIdx.y * 128, n0 = blockIdx.x * 128;

    floatx4 acc[4][4];
    const floatx4 zf = {0.f, 0.f, 0.f, 0.f};
#pragma unroll
    for (int i = 0; i < 4; ++i)
#pragma unroll
        for (int j = 0; j < 4; ++j) acc[i][j] = zf;

    for (int kt = 0; kt < K; kt += 32) {
        __syncthreads();
#pragma unroll
        for (int it = 0; it < 2; ++it) {    // 512 chunks of 16B per matrix
            int cc = it * 256 + t;
            int row = cc >> 2, kc = cc & 3;
            gl_lds16(&A[(size_t)(m0 + row) * K + kt + kc * 8], &As[cc * 8]);
            gl_lds16(&B[(size_t)(n0 + row) * K + kt + kc * 8], &Bs[cc * 8]);
        }
        __syncthreads();
        half8 af[4], bfr[4];
#pragma unroll
        for (int i = 0; i < 4; ++i)
            af[i] = *(const half8*)&As[(wm * 64 + i * 16 + l15) * 32 + quad * 8];
#pragma unroll
        for (int i = 0; i < 4; ++i)
            bfr[i] = *(const half8*)&Bs[(wn * 64 + i * 16 + l15) * 32 + quad * 8];
#pragma unroll
        for (int mi = 0; mi < 4; ++mi)
#pragma unroll
            for (int ni = 0; ni < 4; ++ni)
                acc[mi][ni] = __builtin_amdgcn_mfma_f32_16x16x32_f16(af[mi], bfr[ni],
                                                                     acc[mi][ni], 0, 0, 0);
    }

    // ---- epilogue: two 128x64 col-halves staged through LDS, coalesced writes ----
    const int b = m0 >> 11, s0 = m0 & 2047;
#pragma unroll
    for (int hf = 0; hf < 2; ++hf) {
        __syncthreads();
        if (wn == hf) {
#pragma unroll
            for (int mi = 0; mi < 4; ++mi)
#pragma unroll
                for (int ni = 0; ni < 4; ++ni)
#pragma unroll
                    for (int r = 0; r < 4; ++r)
                        SH[(wm * 64 + mi * 16 + quad * 4 + r) * 68 + ni * 16 + l15] =
                            (_Float16)acc[mi][ni][r];
        }
        __syncthreads();
        const int cbase = n0 + hf * 64;
        if (n0 < 2048) {
            const int hh = (cbase & 1023) >> 6;
            _Float16* dst = (n0 < 1024 ? qh : kh) + (size_t)((b << 4) | hh) * 131072;
#pragma unroll
            for (int it = 0; it < 4; ++it) {
                int cc = it * 256 + t;
                int r = cc >> 3, c8 = cc & 7;
                half4 lo = *(const half4*)&SH[r * 68 + c8 * 8];
                half4 hi = *(const half4*)&SH[r * 68 + c8 * 8 + 4];
                *(half8*)&dst[(size_t)(s0 + r) * 64 + c8 * 8] = from_lohi(lo, hi);
            }
        } else {
            const int hh = (cbase - 2048) >> 6;
            _Float16* dst = vth + (size_t)((b << 4) | hh) * 131072;
#pragma unroll
            for (int it = 0; it < 4; ++it) {
                int cc = it * 256 + t;
                int d = cc >> 4, s8 = cc & 15;
                half8 v;
#pragma unroll
                for (int j = 0; j < 8; ++j) v[j] = SH[(s8 * 8 + j) * 68 + d];
                *(half8*)&dst[(size_t)d * 2048 + s0 + s8 * 8] = v;
            }
        }
    }
}

// ---------------- GEMM2: out = aoh @ woh^T + b_out -> fp32 -----------------------
// M=4096, N=1024, K=1024. 64x128 tile, BK=32, 256 thr, DMA staging.
__global__ __launch_bounds__(256) void gemm_out(const _Float16* __restrict__ A,
                                                const _Float16* __restrict__ B,
                                                float* __restrict__ C,
                                                const float* __restrict__ bias) {
    const int K = 1024, N = 1024;
    __shared__ _Float16 SH[6144];   // As 64x32 (4KB) | Bs 128x32 (8KB)
    _Float16* As = SH;
    _Float16* Bs = SH + 2048;
    const int t = threadIdx.x;
    const int lane = t & 63, w = t >> 6;
    const int l15 = lane & 15, quad = lane >> 4;
    const int wm = w >> 1, wn = w & 1;
    const int m0 = blockIdx.y * 64, n0 = blockIdx.x * 128;

    floatx4 acc[2][4];
    const floatx4 zf = {0.f, 0.f, 0.f, 0.f};
#pragma unroll
    for (int i = 0; i < 2; ++i)
#pragma unroll
        for (int j = 0; j < 4; ++j) acc[i][j] = zf;

    for (int kt = 0; kt < K; kt += 32) {
        __syncthreads();
        {   // A: 256 chunks of 16B
            int row = t >> 2, kc = t & 3;
            gl_lds16(&A[(size_t)(m0 + row) * K + kt + kc * 8], &As[t * 8]);
        }
#pragma unroll
        for (int it = 0; it < 2; ++it) {    // B: 512 chunks of 16B
            int cc = it * 256 + t;
            int row = cc >> 2, kc = cc & 3;
            gl_lds16(&B[(size_t)(n0 + row) * K + kt + kc * 8], &Bs[cc * 8]);
        }
        __syncthreads();
        half8 af[2], bfr[4];
#pragma unroll
        for (int i = 0; i < 2; ++i)
            af[i] = *(const half8*)&As[(wm * 32 + i * 16 + l15) * 32 + quad * 8];
#pragma unroll
        for (int i = 0; i < 4; ++i)
            bfr[i] = *(const half8*)&Bs[(wn * 64 + i * 16 + l15) * 32 + quad * 8];
#pragma unroll
        for (int mi = 0; mi < 2; ++mi)
#pragma unroll
            for (int ni = 0; ni < 4; ++ni)
                acc[mi][ni] = __builtin_amdgcn_mfma_f32_16x16x32_f16(af[mi], bfr[ni],
                                                                     acc[mi][ni], 0, 0, 0);
    }

#pragma unroll
    for (int mi = 0; mi < 2; ++mi) {
#pragma unroll
        for (int ni = 0; ni < 4; ++ni) {
            int col = n0 + wn * 64 + ni * 16 + l15;
            float bv = bias[col];
#pragma unroll
            for (int r = 0; r < 4; ++r) {
                int row = m0 + wm * 32 + mi * 16 + quad * 4 + r;
                C[(size_t)row * N + col] = acc[mi][ni][r] + bv;
            }
        }
    }
}

// ---------------- fused two-pass stablemax attention (S^T form, 8 waves) ---------
// R-new: 512 threads (16 waves/CU vs 8), async global_load_lds staging with
// double-buffered XOR-chunk-swizzled linear [64][64] tiles (T2+T3 2-phase:
// prefetch t+1 issued before compute of t, ONE __syncthreads per tile whose
// implicit vmcnt(0) is exactly the pipeline wait). Swizzle: data chunk (row,c)
// stored at LDS chunk c ^ (row&7); applied identically on the global SOURCE
// address (rule 21) and on every ds_read. Kills the stride-72 bank conflicts
// AND enables DMA staging. Wave w owns 16 q rows (w*16 + l15).
// Q pre-scaled by 0.125; s3 in packed fp16; P never touches LDS
// (permuted-key PV: key(c,quad,j) = c*32 + (j>>2)*16 + quad*4 + (j&3)).
__global__ __launch_bounds__(512, 4) void attn_kernel(const _Float16* __restrict__ qh,
                                                      const _Float16* __restrict__ kh,
                                                      const _Float16* __restrict__ vth,
                                                      _Float16* __restrict__ out) {
    // Ks0 | Ks1 | VTs0 | VTs1, each 64x64 f16 = 8KB -> 32KB total; reused as O-stage
    __shared__ _Float16 SM[16384];

    const int t = threadIdx.x;
    const int lane = t & 63, w = t >> 6;          // 8 waves
    const int l15 = lane & 15, quad = lane >> 4;
    const int sw = l15 & 7;                       // read-side swizzle key (row&7)
    const int q0 = blockIdx.x * 128;
    const int bh = blockIdx.y;
    const int b = bh >> 4, h = bh & 15;

    const _Float16* Qp = qh + (size_t)bh * 131072 + q0 * 64;
    const _Float16* Kp = kh + (size_t)bh * 131072;
    const _Float16* VTp = vth + (size_t)bh * 131072;

    // per-thread staging: one 16B chunk per matrix per tile.
    // dest slot (row = t>>3, cs = t&7) holds global chunk cg = cs ^ (row&7).
    const int srow = t >> 3;
    const int scg = (t & 7) ^ (srow & 7);
    const _Float16* Ksrc = &Kp[(size_t)srow * 64 + scg * 8];     // + kt*64
    const _Float16* Vsrc = &VTp[(size_t)srow * 2048 + scg * 8];  // + kt
    _Float16* Kdst0 = &SM[t * 8];
    _Float16* Kdst1 = &SM[4096 + t * 8];
    _Float16* Vdst0 = &SM[8192 + t * 8];
    _Float16* Vdst1 = &SM[12288 + t * 8];

    const floatx4 zf = {0.f, 0.f, 0.f, 0.f};

    half8 qf[2];   // [kk], pre-scaled by 0.125
#pragma unroll
    for (int kk = 0; kk < 2; ++kk) {
        half8 q = *(const half8*)&Qp[(w * 16 + l15) * 64 + kk * 32 + quad * 8];
#pragma unroll
        for (int j = 0; j < 8; ++j) q[j] = q[j] * (_Float16)0.125f;
        qf[kk] = q;
    }

    // ---------------- pass 1: row max over (scaled) scores --------------------
    float rmax = -1.0e30f;
    gl_lds16(Ksrc, Kdst0);
    __syncthreads();
    for (int kt = 0, cur = 0; kt < 2048; kt += 64, cur ^= 1) {
        if (kt + 64 < 2048)
            gl_lds16(Ksrc + (size_t)(kt + 64) * 64, cur ? Kdst0 : Kdst1);
        const _Float16* Ks = cur ? &SM[4096] : &SM[0];
        floatx4 sa[4];
#pragma unroll
        for (int T = 0; T < 4; ++T) sa[T] = zf;
#pragma unroll
        for (int kk = 0; kk < 2; ++kk) {
            half8 kf[4];
#pragma unroll
            for (int T = 0; T < 4; ++T)
                kf[T] = *(const half8*)&Ks[((T * 16 + l15) << 6) +
                                           ((((kk << 2) + quad) ^ sw) << 3)];
#pragma unroll
            for (int T = 0; T < 4; ++T)
                sa[T] = __builtin_amdgcn_mfma_f32_16x16x32_f16(kf[T], qf[kk], sa[T], 0, 0, 0);
        }
#pragma unroll
        for (int T = 0; T < 4; ++T)
#pragma unroll
            for (int r = 0; r < 4; ++r)
                rmax = fmaxf(rmax, sa[T][r]);
        __syncthreads();
    }
    rmax = fmaxf(rmax, __shfl_xor(rmax, 16, 64));
    rmax = fmaxf(rmax, __shfl_xor(rmax, 32, 64));
    const float xm = -rmax;

    // ---------------- pass 2: p = s3(x); Sum p; P·V ---------------------------
    const half2v cA = {(_Float16)(-1.0f / 6.0f), (_Float16)(-1.0f / 6.0f)};
    const half2v cB = {(_Float16)0.5f, (_Float16)0.5f};
    const half2v cC = {(_Float16)-1.0f, (_Float16)-1.0f};
    const half2v cD = {(_Float16)1.0f, (_Float16)1.0f};

    float rsum = 0.f;
    floatx4 oacc[4];
#pragma unroll
    for (int i = 0; i < 4; ++i) oacc[i] = zf;

    gl_lds16(Ksrc, Kdst0);
    gl_lds16(Vsrc, Vdst0);
    __syncthreads();
    for (int kt = 0, cur = 0; kt < 2048; kt += 64, cur ^= 1) {
        if (kt + 64 < 2048) {
            gl_lds16(Ksrc + (size_t)(kt + 64) * 64, cur ? Kdst0 : Kdst1);
            gl_lds16(Vsrc + (kt + 64), cur ? Vdst0 : Vdst1);
        }
        const _Float16* Ks = cur ? &SM[4096] : &SM[0];
        const _Float16* VTs = cur ? &SM[12288] : &SM[8192];

        floatx4 sa[4];
#pragma unroll
        for (int T = 0; T < 4; ++T) sa[T] = zf;
#pragma unroll
        for (int kk = 0; kk < 2; ++kk) {
            half8 kf[4];
#pragma unroll
            for (int T = 0; T < 4; ++T)
                kf[T] = *(const half8*)&Ks[((T * 16 + l15) << 6) +
                                           ((((kk << 2) + quad) ^ sw) << 3)];
#pragma unroll
            for (int T = 0; T < 4; ++T)
                sa[T] = __builtin_amdgcn_mfma_f32_16x16x32_f16(kf[T], qf[kk], sa[T], 0, 0, 0);
        }
        // PV with permuted key order; s3 in packed fp16 straight into pb
#pragma unroll
        for (int c = 0; c < 2; ++c) {
            half8 vf[4];
#pragma unroll
            for (int di = 0; di < 4; ++di) {
                const int bl = (di * 16 + l15) << 6;
                const int clo = (((c << 2) + (quad >> 1)) ^ sw) << 3;
                const int chi = (((c << 2) + 2 + (quad >> 1)) ^ sw) << 3;
                half4 lo = *(const half4*)&VTs[bl + clo + ((quad & 1) << 2)];
                half4 hi = *(const half4*)&VTs[bl + chi + ((quad & 1) << 2)];
                vf[di] = from_lohi(lo, hi);
            }
            half2v p2m[4];
#pragma unroll
            for (int m = 0; m < 4; ++m) {
                int T = 2 * c + (m >> 1);
                int r0 = (m & 1) * 2;
                half2v x2 = cvt_pk(sa[T][r0] + xm, sa[T][r0 + 1] + xm);
                half2v hp = __builtin_elementwise_fma(x2, cA, cB);
                hp = __builtin_elementwise_fma(x2, hp, cC);
                hp = __builtin_elementwise_fma(x2, hp, cD);
                half2v p2 = rcp2(hp);
                rsum = dot2acc(p2, rsum);
                p2m[m] = p2;
            }
            half8 pb = from4(p2m[0], p2m[1], p2m[2], p2m[3]);
#pragma unroll
            for (int di = 0; di < 4; ++di)
                oacc[di] = __builtin_amdgcn_mfma_f32_16x16x32_f16(vf[di], pb,
                                                                 oacc[di], 0, 0, 0);
        }
        __syncthreads();
    }

    rsum += __shfl_xor(rsum, 16, 64);
    rsum += __shfl_xor(rsum, 32, 64);
    const float inv = 1.0f / rsum;

    // loop-end __syncthreads already separates last reads from O-stage reuse
    _Float16* Os = SM;
#pragma unroll
    for (int di = 0; di < 4; ++di) {
        half4 hv;
#pragma unroll
        for (int r = 0; r < 4; ++r) hv[r] = (_Float16)(oacc[di][r] * inv);
        *(half4*)&Os[(w * 16 + l15) * 72 + di * 16 + quad * 4] = hv;
    }
    __syncthreads();
    _Float16* Op = out + (size_t)(b * 2048 + q0) * 1024 + h * 64;
#pragma unroll
    for (int it = 0; it < 2; ++it) {
        int cc = it * 512 + t;
        int r = cc >> 3, c8 = cc & 7;
        *(half8*)&Op[(size_t)r * 1024 + c8 * 8] = *(const half8*)&Os[r * 72 + c8 * 8];
    }
}

// ---------------- launch ---------------------------------------------------------
extern "C" void kernel_launch(void* const* d_in, const int* in_sizes, int n_in,
                              void* d_out, int out_size, void* d_ws, size_t ws_size,
                              hipStream_t stream) {
    const float* x_f = (const float*)d_in[0];     // [2,2048,1024] fp32
    const float* wqkv_f = (const float*)d_in[1];  // [3072,1024] fp32
    const float* wout_f = (const float*)d_in[2];  // [1024,1024] fp32
    const float* bias_f = (const float*)d_in[3];  // [1024] fp32

    // workspace: 38 MB, with aliasing (aoh reuses xh; woh reuses wqh).
    // ORDERING CONSTRAINT: woh is written only AFTER gemm_qkv consumes wqh.
    char* ws = (char*)d_ws;
    _Float16* xh = (_Float16*)(ws);                   // [4096][1024] f16, 8 MB
    _Float16* aoh = xh;                               // alias: live after gemm_qkv
    _Float16* wqh = (_Float16*)(ws + 8388608);        // [3072][1024] f16, 6 MB
    _Float16* woh = wqh;                              // alias: live after gemm_qkv
    _Float16* qh = (_Float16*)(ws + 14680064);        // [32][2048][64] f16, 8 MB
    _Float16* kh = (_Float16*)(ws + 23068672);        // [32][2048][64] f16, 8 MB
    _Float16* vth = (_Float16*)(ws + 31457280);       // [32][64][2048] f16, 8 MB

    cvt_xw<<<7168, 256, 0, stream>>>((const floatx4*)x_f, (const floatx4*)wqkv_f,
                                     (half4*)xh, (half4*)wqh);
    gemm_qkv<<<dim3(24, 32), 256, 0, stream>>>(xh, wqh, qh, kh, vth);
    cvt_f32_f16<<<1024, 256, 0, stream>>>((const floatx4*)wout_f, (half4*)woh, 262144);
    attn_kernel<<<dim3(16, 32), 512, 0, stream>>>(qh, kh, vth, aoh);
    gemm_out<<<dim3(8, 64), 256, 0, stream>>>(aoh, woh, (float*)d_out, bias_f);
}